// Round 10
// baseline (163.525 us; speedup 1.0000x reference)
//
#include <hip/hip_runtime.h>
#include <hip/hip_bf16.h>

#define NPOS 2744      // 14^3
#define BB 4
#define BNTOT (BB*NPOS)   // 10976
#define RELVOL 19683   // 27^3
#define EROWS2 19688       // padded elems per k-row (mult of 4)
#define NRT 196            // (zm,ym) row-tiles, 16 kslots each (x=0..13 real)
#define NV2 (NRT*2*64)     // 25088 vfrag2 entries
#define N4T 1024           // lc

typedef __bf16 bf16x8 __attribute__((ext_vector_type(8)));
typedef float f32x16 __attribute__((ext_vector_type(16)));
typedef uint4 uint4_a4 __attribute__((aligned(4)));

// ---- workspace layout (bytes) ----
#define WS_Q  0u           // f32 [4][64][2744]
#define WS_K  2809856u     // f32 [4][16][2744]  (dead after k_sl; vfrag2 aliases it)
#define WS_V  3512320u     // f32 [4][16][2744]
#define WS_ST 4214784u     // f32 [160] scale/shift
#define WS_LA 4216192u     // f32 [1088] lc accum: [4][16][17]
#define WS_LC 4220544u     // f32 [4][16][16]
#define WS_E2 4224640u     // u16 [16][EROWS2] bf16 E table, k-MAJOR, single copy (630KB)
#define WS_VF WS_K         // uint4 [196][2][64] v B-fragments, x-row tiling

__device__ inline unsigned short f2bf(float f) {
  unsigned int u = __float_as_uint(f);
  return (unsigned short)((u + 0x7fffu + ((u >> 16) & 1u)) >> 16);
}

__device__ inline unsigned int fsh(unsigned int hi, unsigned int lo, int shbits) {
  return (unsigned int)(((((unsigned long long)hi) << 32) | lo) >> shbits);
}

// ---------------- P1: qkv projections (blocks 0..515) + E-table build + la-zero (516..823) ----------------
__global__ __launch_bounds__(256) void k_qkv(const float* __restrict__ x,
    const float* __restrict__ Wq, const float* __restrict__ Wk, const float* __restrict__ Wv,
    const float* __restrict__ rpe,
    float* __restrict__ qws, float* __restrict__ kws, float* __restrict__ vws,
    unsigned short* __restrict__ ebf, float* __restrict__ la) {
  int bid = blockIdx.x;
  int tid = threadIdx.x;
  if (bid >= 516) {
    int bid2 = bid - 516;                      // 0..307
    if (bid2 == 0 && tid < 272) ((float4*)la)[tid] = make_float4(0.f, 0.f, 0.f, 0.f);
    const int TOT = 16 * EROWS2;
    for (int e = bid2 * 256 + tid; e < TOT; e += 308 * 256) {
      int k = e / EROWS2;
      int i = e - k * EROWS2;
      float val = (i < RELVOL) ? rpe[i * 16 + k] : 0.f;
      ebf[e] = f2bf(val);
    }
    return;
  }
  int cg = bid % 12, nb = bid / 12;
  int gid = nb * 256 + tid;
  if (gid >= BNTOT) return;
  int b = gid / NPOS, n = gid - b * NPOS;
  const float* xp = x + (size_t)b * 64 * NPOS + n;
  int ch0 = cg * 8;
  const float* wbase;
  float* obase;
  if (ch0 < 64)      { wbase = Wq + ch0 * 64;        obase = qws + ((size_t)b * 64 + ch0) * NPOS + n; }
  else if (ch0 < 80) { wbase = Wk + (ch0 - 64) * 64; obase = kws + ((size_t)b * 16 + (ch0 - 64)) * NPOS + n; }
  else               { wbase = Wv + (ch0 - 80) * 64; obase = vws + ((size_t)b * 16 + (ch0 - 80)) * NPOS + n; }

  float acc[8];
#pragma unroll
  for (int j = 0; j < 8; ++j) acc[j] = 0.f;
  for (int c = 0; c < 64; c += 4) {
    float x0 = xp[(c + 0) * NPOS], x1 = xp[(c + 1) * NPOS];
    float x2 = xp[(c + 2) * NPOS], x3 = xp[(c + 3) * NPOS];
#pragma unroll
    for (int j = 0; j < 8; ++j) {
      float4 w = *(const float4*)(wbase + j * 64 + c);
      acc[j] += w.x * x0 + w.y * x1 + w.z * x2 + w.w * x3;
    }
  }
#pragma unroll
  for (int j = 0; j < 8; ++j) obase[(size_t)j * NPOS] = acc[j];
}

// ---------------- P2: BN stats+finalize (blocks 0..79) | lambda_c partials (80..335) ----------------
__global__ __launch_bounds__(256) void k_sl(const float* __restrict__ qws,
    const float* __restrict__ kws, const float* __restrict__ vws,
    const float* __restrict__ gq, const float* __restrict__ bq,
    const float* __restrict__ gv, const float* __restrict__ bv,
    float* __restrict__ st, float* __restrict__ lcacc) {
  int bid = blockIdx.x;
  int tid = threadIdx.x;
  int wid = tid >> 6;
  __shared__ float red[17][4];
  if (bid < 80) {
    int ch = bid;
    const float* p = (ch < 64) ? (qws + (size_t)ch * NPOS) : (vws + (size_t)(ch - 64) * NPOS);
    size_t pstride = (ch < 64) ? (size_t)64 * NPOS : (size_t)16 * NPOS;
    float s = 0.f, ss = 0.f;
    for (int b = 0; b < 4; ++b) {
      const float* pp = p + b * pstride;
      for (int n = tid; n < NPOS; n += 256) { float v = pp[n]; s += v; ss += v * v; }
    }
#pragma unroll
    for (int o = 32; o > 0; o >>= 1) { s += __shfl_xor(s, o, 64); ss += __shfl_xor(ss, o, 64); }
    if ((tid & 63) == 0) { red[0][wid] = s; red[1][wid] = ss; }
    __syncthreads();
    if (tid == 0) {
      float S = red[0][0] + red[0][1] + red[0][2] + red[0][3];
      float SS = red[1][0] + red[1][1] + red[1][2] + red[1][3];
      float mean = S / (float)BNTOT;
      float var = SS / (float)BNTOT - mean * mean;
      float inv = rsqrtf(var + 1e-5f);
      float g, be;
      if (ch < 64) { g = gq[ch]; be = bq[ch]; } else { g = gv[ch - 64]; be = bv[ch - 64]; }
      float sc = g * inv, sh = be - mean * sc;
      if (ch < 64) { st[ch] = sc; st[64 + ch] = sh; }
      else { st[128 + (ch - 64)] = sc; st[144 + (ch - 64)] = sh; }
    }
  } else {
    int bid2 = bid - 80;
    int b = bid2 >> 6, kc = (bid2 >> 2) & 15, seg = bid2 & 3;
    const float* kp = kws + ((size_t)b * 16 + kc) * NPOS;
    const float* vp = vws + (size_t)b * 16 * NPOS;
    float s = 0.f, acc[16];
#pragma unroll
    for (int v = 0; v < 16; ++v) acc[v] = 0.f;
    int m0 = seg * 686;
    for (int m = m0 + tid; m < m0 + 686; m += 256) {
      float e = __expf(kp[m]);
      s += e;
#pragma unroll
      for (int v = 0; v < 16; ++v) acc[v] += e * vp[(size_t)v * NPOS + m];
    }
#pragma unroll
    for (int o = 32; o > 0; o >>= 1) {
      s += __shfl_xor(s, o, 64);
#pragma unroll
      for (int v = 0; v < 16; ++v) acc[v] += __shfl_xor(acc[v], o, 64);
    }
    if ((tid & 63) == 0) { red[16][wid] = s; for (int v = 0; v < 16; ++v) red[v][wid] = acc[v]; }
    __syncthreads();
    if (tid < 17) {
      float tot = red[tid][0] + red[tid][1] + red[tid][2] + red[tid][3];
      atomicAdd(lcacc + ((size_t)b * 16 + kc) * 17 + tid, tot);
    }
  }
}

// ---------------- P3: vfrag2 (x-row tiling) + lc finalize (102 blocks * 256 = 26112) ----------------
__global__ __launch_bounds__(256) void k_conv2(const float* __restrict__ vws,
    const float* __restrict__ st, const float* __restrict__ lcacc,
    uint4* __restrict__ vfrag, float* __restrict__ lc) {
  int idx = blockIdx.x * 256 + threadIdx.x;
  if (idx < NV2) {
    int rt = idx >> 7; int r = idx & 127;
    int ct = r >> 6, l = r & 63;
    int zm = rt / 14, ym = rt - zm * 14;
    int kh = l >> 5;
    int b = ct * 2 + ((l >> 4) & 1), v = l & 15;
    int mrow = zm * 196 + ym * 14;
    float sc = st[128 + v], sh = st[144 + v];
    unsigned int wds[4];
#pragma unroll
    for (int i = 0; i < 4; ++i) {
      int x0 = kh * 8 + 2 * i, x1 = x0 + 1;
      float f0 = 0.f, f1 = 0.f;
      if (x0 < 14) f0 = vws[((size_t)b * 16 + v) * NPOS + mrow + x0] * sc + sh;
      if (x1 < 14) f1 = vws[((size_t)b * 16 + v) * NPOS + mrow + x1] * sc + sh;
      wds[i] = (unsigned int)f2bf(f0) | ((unsigned int)f2bf(f1) << 16);
    }
    vfrag[(rt * 2 + ct) * 64 + l] = make_uint4(wds[0], wds[1], wds[2], wds[3]);
  } else if (idx < NV2 + N4T) {
    int t = idx - NV2;
    int b = t >> 8, kc = (t >> 4) & 15, v = t & 15;
    const float* la = lcacc + ((size_t)b * 16 + kc) * 17;
    float S = la[16];
    lc[((size_t)b * 16 + kc) * 16 + v] = st[128 + v] * (la[v] / S) + st[144 + v];
  }
}

// ---------------- P4: main lambda_p MFMA kernel (direct A-gather, single-copy table) ----------------
// 686 blocks (XCD-swizzled) * 256 thr (4 waves). Block g owns n-quad {4g..4g+3} as 2
// n-pairs P,Q. Wave w = m-quarter: rt in [w*49, w*49+49). Per rt lane loads its A
// fragment as aligned dwordx4+dword at (s&~1) and funnel-shifts by (s&1)*16 bits at
// USE time (raw words prefetched 1 iter ahead). B from vfrag2; 4 MFMAs (2np x 2ct).
__global__ __launch_bounds__(256, 3) void k_lam(const unsigned short* __restrict__ ebf,
    const uint4* __restrict__ vfrag, const float* __restrict__ qws,
    const float* __restrict__ st, const float* __restrict__ lc, float* __restrict__ out) {
  __shared__ float red[8192];   // 32 KB reduction scratch
  int tid = threadIdx.x;
  int w = tid >> 6, l = tid & 63;
  // bijective XCD swizzle: 686 = 8*85 + 6
  int orig = blockIdx.x;
  int xcd = orig & 7, bi = orig >> 3;
  int g = (xcd < 6) ? (xcd * 86 + bi) : (516 + (xcd - 6) * 85 + bi);
  int arow = l & 31;
  int nsel = arow >> 4, kq = arow & 15;
  int kh = l >> 5;

  // element-base for the two n's this lane serves (np P: n=4g+nsel; np Q: n=4g+2+nsel)
  int ebase[2];
#pragma unroll
  for (int sq = 0; sq < 2; ++sq) {
    int n = g * 4 + sq * 2 + nsel;
    int zn = n / 196; int t0 = n - zn * 196; int yn = t0 / 14; int xn = t0 - yn * 14;
    ebase[sq] = kq * EROWS2 + (13 - zn) * 729 + (13 - yn) * 27 + (13 - xn) + kh * 8;
  }
  int ebP = ebase[0], ebQ = ebase[1];

  f32x16 acc0, acc1, acc2, acc3;
#pragma unroll
  for (int i = 0; i < 16; ++i) { acc0[i] = 0.f; acc1[i] = 0.f; acc2[i] = 0.f; acc3[i] = 0.f; }

  int rt0 = w * 49;
  // prologue raw loads for rt0
  uint4 cPa, cQa, B0, B1;
  unsigned int cPe, cQe;
  int cPs, cQs;
  {
    int zm = rt0 / 14, ym = rt0 - zm * 14;
    int ro = zm * 729 + ym * 27;
    int sP = ebP + ro, sQ = ebQ + ro;
    const unsigned short* pP = ebf + (sP & ~1);
    const unsigned short* pQ = ebf + (sQ & ~1);
    cPa = *(const uint4_a4*)pP; cPe = *(const unsigned int*)(pP + 8); cPs = (sP & 1) << 4;
    cQa = *(const uint4_a4*)pQ; cQe = *(const unsigned int*)(pQ + 8); cQs = (sQ & 1) << 4;
    const uint4* vf = vfrag + (size_t)(rt0 * 2) * 64 + l;
    B0 = vf[0]; B1 = vf[64];
  }

  for (int d = 0; d < 49; ++d) {
    int rt1 = rt0 + d + ((d < 48) ? 1 : 0);
    int zm = rt1 / 14, ym = rt1 - zm * 14;
    int ro = zm * 729 + ym * 27;
    int sP = ebP + ro, sQ = ebQ + ro;
    const unsigned short* pP = ebf + (sP & ~1);
    const unsigned short* pQ = ebf + (sQ & ~1);
    uint4 nPa = *(const uint4_a4*)pP;
    unsigned int nPe = *(const unsigned int*)(pP + 8);
    uint4 nQa = *(const uint4_a4*)pQ;
    unsigned int nQe = *(const unsigned int*)(pQ + 8);
    int nPs = (sP & 1) << 4, nQs = (sQ & 1) << 4;
    const uint4* vf = vfrag + (size_t)(rt1 * 2) * 64 + l;
    uint4 nB0 = vf[0], nB1 = vf[64];
    // align current raw -> fragments (funnel shift by 0 or 16 bits)
    uint4 AP, AQ;
    AP.x = fsh(cPa.y, cPa.x, cPs); AP.y = fsh(cPa.z, cPa.y, cPs);
    AP.z = fsh(cPa.w, cPa.z, cPs); AP.w = fsh(cPe,   cPa.w, cPs);
    AQ.x = fsh(cQa.y, cQa.x, cQs); AQ.y = fsh(cQa.z, cQa.y, cQs);
    AQ.z = fsh(cQa.w, cQa.z, cQs); AQ.w = fsh(cQe,   cQa.w, cQs);
    __builtin_amdgcn_s_setprio(1);
    acc0 = __builtin_amdgcn_mfma_f32_32x32x16_bf16(
        __builtin_bit_cast(bf16x8, AP), __builtin_bit_cast(bf16x8, B0), acc0, 0, 0, 0);
    acc1 = __builtin_amdgcn_mfma_f32_32x32x16_bf16(
        __builtin_bit_cast(bf16x8, AP), __builtin_bit_cast(bf16x8, B1), acc1, 0, 0, 0);
    acc2 = __builtin_amdgcn_mfma_f32_32x32x16_bf16(
        __builtin_bit_cast(bf16x8, AQ), __builtin_bit_cast(bf16x8, B0), acc2, 0, 0, 0);
    acc3 = __builtin_amdgcn_mfma_f32_32x32x16_bf16(
        __builtin_bit_cast(bf16x8, AQ), __builtin_bit_cast(bf16x8, B1), acc3, 0, 0, 0);
    __builtin_amdgcn_s_setprio(0);
    cPa = nPa; cPe = nPe; cPs = nPs;
    cQa = nQa; cQe = nQe; cQs = nQs;
    B0 = nB0; B1 = nB1;
  }

  // ---- tree reduction across 4 m-quarter waves ----
  if (w >= 2) {
    float* r0 = red + (w - 2) * 4096;
#pragma unroll
    for (int r = 0; r < 16; ++r) {
      r0[r * 64 + l] = acc0[r];         r0[1024 + r * 64 + l] = acc1[r];
      r0[2048 + r * 64 + l] = acc2[r];  r0[3072 + r * 64 + l] = acc3[r];
    }
  }
  __syncthreads();
  if (w < 2) {
    const float* r0 = red + w * 4096;
#pragma unroll
    for (int r = 0; r < 16; ++r) {
      acc0[r] += r0[r * 64 + l];        acc1[r] += r0[1024 + r * 64 + l];
      acc2[r] += r0[2048 + r * 64 + l]; acc3[r] += r0[3072 + r * 64 + l];
    }
  }
  __syncthreads();
  if (w == 1) {
#pragma unroll
    for (int r = 0; r < 16; ++r) {
      red[r * 64 + l] = acc0[r];         red[1024 + r * 64 + l] = acc1[r];
      red[2048 + r * 64 + l] = acc2[r];  red[3072 + r * 64 + l] = acc3[r];
    }
  }
  __syncthreads();
  if (w == 0) {
#pragma unroll
    for (int r = 0; r < 16; ++r) {
      acc0[r] += red[r * 64 + l];        acc1[r] += red[1024 + r * 64 + l];
      acc2[r] += red[2048 + r * 64 + l]; acc3[r] += red[3072 + r * 64 + l];
    }
    int sig = kh;
    int bsel = (l >> 4) & 1, v = l & 15;
#pragma unroll
    for (int sq = 0; sq < 2; ++sq) {
      int np = g * 2 + sq;
#pragma unroll
      for (int ct = 0; ct < 2; ++ct) {
        int b = ct * 2 + bsel;
        float lam[16];
#pragma unroll
        for (int r = 0; r < 16; ++r) {
          int kk = (r & 3) + 4 * sig + 8 * ((r >> 2) & 1);
          float av = sq ? (ct ? acc3[r] : acc2[r]) : (ct ? acc1[r] : acc0[r]);
          lam[r] = av + lc[((size_t)b * 16 + kk) * 16 + v];
        }
#pragma unroll
        for (int ns = 0; ns < 2; ++ns) {
          int n = np * 2 + ns;
#pragma unroll
          for (int h = 0; h < 4; ++h) {
            float part = 0.f;
#pragma unroll
            for (int rr = 0; rr < 8; ++rr) {
              int kk = (rr & 3) + 4 * sig + 8 * ((rr >> 2) & 1);
              int ch = h * 16 + kk;
              float qv = qws[((size_t)b * 64 + ch) * NPOS + n] * st[ch] + st[64 + ch];
              part += qv * lam[ns * 8 + rr];
            }
            part += __shfl_xor(part, 32, 64);
            if (sig == 0) out[((size_t)b * 64 + h * 16 + v) * NPOS + n] = part;
          }
        }
      }
    }
  }
}

extern "C" void kernel_launch(void* const* d_in, const int* in_sizes, int n_in,
                              void* d_out, int out_size, void* d_ws, size_t ws_size,
                              hipStream_t stream) {
  const float* x   = (const float*)d_in[0];
  const float* Wq  = (const float*)d_in[1];
  const float* Wk  = (const float*)d_in[2];
  const float* Wv  = (const float*)d_in[3];
  const float* rpe = (const float*)d_in[4];
  const float* gq  = (const float*)d_in[5];
  const float* bq  = (const float*)d_in[6];
  const float* gv  = (const float*)d_in[7];
  const float* bv  = (const float*)d_in[8];
  float* out = (float*)d_out;
  char* ws = (char*)d_ws;
  float* qws = (float*)(ws + WS_Q);
  float* kws = (float*)(ws + WS_K);
  float* vws = (float*)(ws + WS_V);
  float* st  = (float*)(ws + WS_ST);
  float* la  = (float*)(ws + WS_LA);
  float* lcp = (float*)(ws + WS_LC);
  unsigned short* ebf = (unsigned short*)(ws + WS_E2);
  uint4* vfrag = (uint4*)(ws + WS_VF);

  k_qkv<<<824, 256, 0, stream>>>(x, Wq, Wk, Wv, rpe, qws, kws, vws, ebf, la);
  k_sl<<<336, 256, 0, stream>>>(qws, kws, vws, gq, bq, gv, bv, st, la);
  k_conv2<<<102, 256, 0, stream>>>(vws, st, la, vfrag, lcp);
  k_lam<<<686, 256, 0, stream>>>(ebf, vfrag, qws, st, lcp, out);
}

// Round 11
// 66.169 us; speedup vs baseline: 2.4713x; 2.4713x over previous
//
#include <hip/hip_runtime.h>
#include <hip/hip_bf16.h>

#define NPOS 2744      // 14^3
#define BB 4
#define BNTOT (BB*NPOS)   // 10976
#define RELVOL 19683   // 27^3
#define EROWS2 19688       // padded elems per k-row (mult of 4)
#define NRT 196            // (zm,ym) m-row-tiles, 16 kslots each (x=0..13 real)
#define NV2 (NRT*2*64)     // 25088 vfrag entries
#define N4T 1024           // lc
#define WCOPY 10368        // LDS window elems per copy
#define WDW 5184           // dwords per copy (WCOPY/2)
#define NGRP 43            // 64-n groups

typedef __bf16 bf16x8 __attribute__((ext_vector_type(8)));
typedef float f32x16 __attribute__((ext_vector_type(16)));

// ---- workspace layout (bytes) ----
#define WS_Q  0u           // f32 [4][64][2744]
#define WS_K  2809856u     // f32 [4][16][2744]  (dead after k_sl; vfrag aliases it)
#define WS_V  3512320u     // f32 [4][16][2744]
#define WS_ST 4214784u     // f32 [160] scale/shift
#define WS_LA 4216192u     // f32 [1088] lc accum
#define WS_LC 4220544u     // f32 [4][16][16]
#define WS_E2 4224640u     // u16 [16][EROWS2] bf16 E table, k-MAJOR (630KB) + 2KB pad
#define WS_LP 4856704u     // u32 [16][43][2][2][8][64] packed bf16 lambda_p (5.64MB)
#define WS_VF WS_K         // uint4 [196][2][64] v B-fragments

__device__ inline unsigned short f2bf(float f) {
  unsigned int u = __float_as_uint(f);
  return (unsigned short)((u + 0x7fffu + ((u >> 16) & 1u)) >> 16);
}
__device__ inline unsigned int fsh(unsigned int hi, unsigned int lo, int shbits) {
  return (unsigned int)(((((unsigned long long)hi) << 32) | lo) >> shbits);
}
__device__ inline unsigned int pk2(float a, float b) {
  return (unsigned int)f2bf(a) | ((unsigned int)f2bf(b) << 16);
}

// ---------------- P1: qkv projections (blocks 0..515) + E-table build + la-zero (516..823) ----------------
__global__ __launch_bounds__(256) void k_qkv(const float* __restrict__ x,
    const float* __restrict__ Wq, const float* __restrict__ Wk, const float* __restrict__ Wv,
    const float* __restrict__ rpe,
    float* __restrict__ qws, float* __restrict__ kws, float* __restrict__ vws,
    unsigned short* __restrict__ ebf, float* __restrict__ la) {
  int bid = blockIdx.x;
  int tid = threadIdx.x;
  if (bid >= 516) {
    int bid2 = bid - 516;                      // 0..307
    if (bid2 == 0 && tid < 272) ((float4*)la)[tid] = make_float4(0.f, 0.f, 0.f, 0.f);
    const int TOT = 16 * EROWS2 + 1024;        // +1024 elems: zero the 2KB pad after table
    for (int e = bid2 * 256 + tid; e < TOT; e += 308 * 256) {
      if (e < 16 * EROWS2) {
        int k = e / EROWS2;
        int i = e - k * EROWS2;
        float val = (i < RELVOL) ? rpe[i * 16 + k] : 0.f;
        ebf[e] = f2bf(val);
      } else {
        ebf[e] = 0;
      }
    }
    return;
  }
  int cg = bid % 12, nb = bid / 12;
  int gid = nb * 256 + tid;
  if (gid >= BNTOT) return;
  int b = gid / NPOS, n = gid - b * NPOS;
  const float* xp = x + (size_t)b * 64 * NPOS + n;
  int ch0 = cg * 8;
  const float* wbase;
  float* obase;
  if (ch0 < 64)      { wbase = Wq + ch0 * 64;        obase = qws + ((size_t)b * 64 + ch0) * NPOS + n; }
  else if (ch0 < 80) { wbase = Wk + (ch0 - 64) * 64; obase = kws + ((size_t)b * 16 + (ch0 - 64)) * NPOS + n; }
  else               { wbase = Wv + (ch0 - 80) * 64; obase = vws + ((size_t)b * 16 + (ch0 - 80)) * NPOS + n; }

  float acc[8];
#pragma unroll
  for (int j = 0; j < 8; ++j) acc[j] = 0.f;
  for (int c = 0; c < 64; c += 4) {
    float x0 = xp[(c + 0) * NPOS], x1 = xp[(c + 1) * NPOS];
    float x2 = xp[(c + 2) * NPOS], x3 = xp[(c + 3) * NPOS];
#pragma unroll
    for (int j = 0; j < 8; ++j) {
      float4 w = *(const float4*)(wbase + j * 64 + c);
      acc[j] += w.x * x0 + w.y * x1 + w.z * x2 + w.w * x3;
    }
  }
#pragma unroll
  for (int j = 0; j < 8; ++j) obase[(size_t)j * NPOS] = acc[j];
}

// ---------------- P2: BN stats+finalize (blocks 0..79) | lambda_c partials (80..335) ----------------
__global__ __launch_bounds__(256) void k_sl(const float* __restrict__ qws,
    const float* __restrict__ kws, const float* __restrict__ vws,
    const float* __restrict__ gq, const float* __restrict__ bq,
    const float* __restrict__ gv, const float* __restrict__ bv,
    float* __restrict__ st, float* __restrict__ lcacc) {
  int bid = blockIdx.x;
  int tid = threadIdx.x;
  int wid = tid >> 6;
  __shared__ float red[17][4];
  if (bid < 80) {
    int ch = bid;
    const float* p = (ch < 64) ? (qws + (size_t)ch * NPOS) : (vws + (size_t)(ch - 64) * NPOS);
    size_t pstride = (ch < 64) ? (size_t)64 * NPOS : (size_t)16 * NPOS;
    float s = 0.f, ss = 0.f;
    for (int b = 0; b < 4; ++b) {
      const float* pp = p + b * pstride;
      for (int n = tid; n < NPOS; n += 256) { float v = pp[n]; s += v; ss += v * v; }
    }
#pragma unroll
    for (int o = 32; o > 0; o >>= 1) { s += __shfl_xor(s, o, 64); ss += __shfl_xor(ss, o, 64); }
    if ((tid & 63) == 0) { red[0][wid] = s; red[1][wid] = ss; }
    __syncthreads();
    if (tid == 0) {
      float S = red[0][0] + red[0][1] + red[0][2] + red[0][3];
      float SS = red[1][0] + red[1][1] + red[1][2] + red[1][3];
      float mean = S / (float)BNTOT;
      float var = SS / (float)BNTOT - mean * mean;
      float inv = rsqrtf(var + 1e-5f);
      float g, be;
      if (ch < 64) { g = gq[ch]; be = bq[ch]; } else { g = gv[ch - 64]; be = bv[ch - 64]; }
      float sc = g * inv, sh = be - mean * sc;
      if (ch < 64) { st[ch] = sc; st[64 + ch] = sh; }
      else { st[128 + (ch - 64)] = sc; st[144 + (ch - 64)] = sh; }
    }
  } else {
    int bid2 = bid - 80;
    int b = bid2 >> 6, kc = (bid2 >> 2) & 15, seg = bid2 & 3;
    const float* kp = kws + ((size_t)b * 16 + kc) * NPOS;
    const float* vp = vws + (size_t)b * 16 * NPOS;
    float s = 0.f, acc[16];
#pragma unroll
    for (int v = 0; v < 16; ++v) acc[v] = 0.f;
    int m0 = seg * 686;
    for (int m = m0 + tid; m < m0 + 686; m += 256) {
      float e = __expf(kp[m]);
      s += e;
#pragma unroll
      for (int v = 0; v < 16; ++v) acc[v] += e * vp[(size_t)v * NPOS + m];
    }
#pragma unroll
    for (int o = 32; o > 0; o >>= 1) {
      s += __shfl_xor(s, o, 64);
#pragma unroll
      for (int v = 0; v < 16; ++v) acc[v] += __shfl_xor(acc[v], o, 64);
    }
    if ((tid & 63) == 0) { red[16][wid] = s; for (int v = 0; v < 16; ++v) red[v][wid] = acc[v]; }
    __syncthreads();
    if (tid < 17) {
      float tot = red[tid][0] + red[tid][1] + red[tid][2] + red[tid][3];
      atomicAdd(lcacc + ((size_t)b * 16 + kc) * 17 + tid, tot);
    }
  }
}

// ---------------- P3: vfrag (x-row tiling) + lc finalize ----------------
__global__ __launch_bounds__(256) void k_conv2(const float* __restrict__ vws,
    const float* __restrict__ st, const float* __restrict__ lcacc,
    uint4* __restrict__ vfrag, float* __restrict__ lc) {
  int idx = blockIdx.x * 256 + threadIdx.x;
  if (idx < NV2) {
    int rt = idx >> 7; int r = idx & 127;
    int ct = r >> 6, l = r & 63;
    int zm = rt / 14, ym = rt - zm * 14;
    int kh = l >> 5;
    int b = ct * 2 + ((l >> 4) & 1), v = l & 15;
    int mrow = zm * 196 + ym * 14;
    float sc = st[128 + v], sh = st[144 + v];
    unsigned int wds[4];
#pragma unroll
    for (int i = 0; i < 4; ++i) {
      int x0 = kh * 8 + 2 * i, x1 = x0 + 1;
      float f0 = 0.f, f1 = 0.f;
      if (x0 < 14) f0 = vws[((size_t)b * 16 + v) * NPOS + mrow + x0] * sc + sh;
      if (x1 < 14) f1 = vws[((size_t)b * 16 + v) * NPOS + mrow + x1] * sc + sh;
      wds[i] = (unsigned int)f2bf(f0) | ((unsigned int)f2bf(f1) << 16);
    }
    vfrag[(rt * 2 + ct) * 64 + l] = make_uint4(wds[0], wds[1], wds[2], wds[3]);
  } else if (idx < NV2 + N4T) {
    int t = idx - NV2;
    int b = t >> 8, kc = (t >> 4) & 15, v = t & 15;
    const float* la = lcacc + ((size_t)b * 16 + kc) * 17;
    float S = la[16];
    lc[((size_t)b * 16 + kc) * 16 + v] = st[128 + v] * (la[v] / S) + st[144 + v];
  }
}

// ---------------- P4: lambda_p — per-k LDS-windowed MFMA ----------------
// 688 blocks = 16 k x 43 n-groups (64 n). Stage table window [b0, b0+WCOPY) of row k
// into LDS twice (copy B shifted +1 elem) -> every A fragment = 4 aligned LDS dwords.
// 4 waves = m-quarters (49 x-rows each); per step: 2 A frags (LDS) + 2 B (L2, shared
// by both n-tiles) + 4 MFMA. Tree-reduce over waves, store packed-bf16 lambda_p.
__global__ __launch_bounds__(256, 3) void k_lam(const unsigned short* __restrict__ ebf,
    const uint4* __restrict__ vfrag, unsigned int* __restrict__ lpb) {
  __shared__ unsigned int lds[WCOPY];
  int tid = threadIdx.x;
  int w = tid >> 6, l = tid & 63;
  int bid = blockIdx.x;
  int k = bid / NGRP, ng = bid - k * NGRP;
  int n0 = ng * 64;
  int nmax = min(n0 + 63, NPOS - 1);
  int zx = nmax / 196, tx = nmax - zx * 196, yx = tx / 14, xx = tx - yx * 14;
  int b0 = (9841 - (zx * 729 + yx * 27 + xx)) & ~7;   // 16B-aligned window start

  // stage window + shifted copy (global dwords aligned; overrun covered by table pad)
  const unsigned int* gsrc = (const unsigned int*)(ebf + (size_t)k * EROWS2 + b0);
#pragma unroll
  for (int it = 0; it < 6; ++it) {
    int ck = it * 256 + tid;
    if (ck < WDW / 4) {
      uint4 g = *(const uint4*)(gsrc + 4 * ck);
      unsigned int g4 = gsrc[4 * ck + 4];
      *(uint4*)(&lds[4 * ck]) = g;
      uint4 h;
      h.x = fsh(g.y, g.x, 16); h.y = fsh(g.z, g.y, 16);
      h.z = fsh(g.w, g.z, 16); h.w = fsh(g4, g.w, 16);
      *(uint4*)(&lds[WDW + 4 * ck]) = h;
    }
  }
  int i = l & 31, kh = l >> 5;
  int n_a = min(n0 + i, NPOS - 1);
  int n_b = min(n0 + 32 + i, NPOS - 1);
  int za = n_a / 196, ta = n_a - za * 196, ya = ta / 14, xa = ta - ya * 14;
  int zb = n_b / 196, tb = n_b - zb * 196, yb = tb / 14, xb = tb - yb * 14;
  int soff0 = (9841 - (za * 729 + ya * 27 + xa)) - b0 + kh * 8;
  int soff1 = (9841 - (zb * 729 + yb * 27 + xb)) - b0 + kh * 8;
  __syncthreads();

  f32x16 a00, a01, a10, a11;
#pragma unroll
  for (int q = 0; q < 16; ++q) { a00[q] = 0.f; a01[q] = 0.f; a10[q] = 0.f; a11[q] = 0.f; }

  int rt0 = w * 49;
  const uint4* vf = vfrag + l;
  uint4 B0 = vf[(size_t)(rt0 * 2) * 64], B1 = vf[(size_t)(rt0 * 2 + 1) * 64];
  for (int d = 0; d < 49; ++d) {
    int rt = rt0 + d;
    int rtn = (d < 48) ? (rt + 1) : rt;
    uint4 nB0 = vf[(size_t)(rtn * 2) * 64], nB1 = vf[(size_t)(rtn * 2 + 1) * 64];
    int zm = rt / 14, ym = rt - zm * 14;
    int crow = zm * 729 + ym * 27;
    int o0 = soff0 + crow, o1 = soff1 + crow;
    int ad0 = (o0 >> 1) + (o0 & 1) * WDW;
    int ad1 = (o1 >> 1) + (o1 & 1) * WDW;
    uint4 A0 = make_uint4(lds[ad0], lds[ad0 + 1], lds[ad0 + 2], lds[ad0 + 3]);
    uint4 A1 = make_uint4(lds[ad1], lds[ad1 + 1], lds[ad1 + 2], lds[ad1 + 3]);
    __builtin_amdgcn_s_setprio(1);
    a00 = __builtin_amdgcn_mfma_f32_32x32x16_bf16(
        __builtin_bit_cast(bf16x8, A0), __builtin_bit_cast(bf16x8, B0), a00, 0, 0, 0);
    a01 = __builtin_amdgcn_mfma_f32_32x32x16_bf16(
        __builtin_bit_cast(bf16x8, A0), __builtin_bit_cast(bf16x8, B1), a01, 0, 0, 0);
    a10 = __builtin_amdgcn_mfma_f32_32x32x16_bf16(
        __builtin_bit_cast(bf16x8, A1), __builtin_bit_cast(bf16x8, B0), a10, 0, 0, 0);
    a11 = __builtin_amdgcn_mfma_f32_32x32x16_bf16(
        __builtin_bit_cast(bf16x8, A1), __builtin_bit_cast(bf16x8, B1), a11, 0, 0, 0);
    __builtin_amdgcn_s_setprio(0);
    B0 = nB0; B1 = nB1;
  }

  // ---- tree reduction over m-quarter waves (reuse window LDS) ----
  __syncthreads();
  float* red = (float*)lds;
  if (w >= 2) {
    float* r0 = red + (w - 2) * 4096;
#pragma unroll
    for (int r = 0; r < 16; ++r) {
      r0[r * 64 + l] = a00[r];          r0[1024 + r * 64 + l] = a01[r];
      r0[2048 + r * 64 + l] = a10[r];   r0[3072 + r * 64 + l] = a11[r];
    }
  }
  __syncthreads();
  if (w < 2) {
    const float* r0 = red + w * 4096;
#pragma unroll
    for (int r = 0; r < 16; ++r) {
      a00[r] += r0[r * 64 + l];         a01[r] += r0[1024 + r * 64 + l];
      a10[r] += r0[2048 + r * 64 + l];  a11[r] += r0[3072 + r * 64 + l];
    }
  }
  __syncthreads();
  if (w == 1) {
#pragma unroll
    for (int r = 0; r < 16; ++r) {
      red[r * 64 + l] = a00[r];         red[1024 + r * 64 + l] = a01[r];
      red[2048 + r * 64 + l] = a10[r];  red[3072 + r * 64 + l] = a11[r];
    }
  }
  __syncthreads();
  if (w == 0) {
#pragma unroll
    for (int r = 0; r < 16; ++r) {
      a00[r] += red[r * 64 + l];        a01[r] += red[1024 + r * 64 + l];
      a10[r] += red[2048 + r * 64 + l]; a11[r] += red[3072 + r * 64 + l];
    }
    // store packed bf16 lambda_p: [k][ng][nt][ct][rp][64]
    size_t base = (size_t)(k * NGRP + ng) * 2048;
#pragma unroll
    for (int rp = 0; rp < 8; ++rp) {
      lpb[base + (size_t)(0 * 8 + rp) * 64 + l]  = pk2(a00[2 * rp], a00[2 * rp + 1]);
      lpb[base + (size_t)(1 * 8 + rp) * 64 + l]  = pk2(a01[2 * rp], a01[2 * rp + 1]);
      lpb[base + (size_t)(2 * 8 + rp) * 64 + l]  = pk2(a10[2 * rp], a10[2 * rp + 1]);
      lpb[base + (size_t)(3 * 8 + rp) * 64 + l]  = pk2(a11[2 * rp], a11[2 * rp + 1]);
    }
  }
}

// ---------------- P5: epilogue out = q_bn . (lambda_p + lambda_c) ----------------
__global__ __launch_bounds__(256) void k_ep(const unsigned int* __restrict__ lpb,
    const float* __restrict__ qws, const float* __restrict__ st,
    const float* __restrict__ lc, float* __restrict__ out) {
  int gid = blockIdx.x * 256 + threadIdx.x;
  if (gid >= BNTOT) return;
  int b = gid / NPOS, n = gid - b * NPOS;
  int ng = n >> 6, loc = n & 63, nt = loc >> 5, i = loc & 31;
  int kh = (i >> 2) & 1;
  int r = (i & 3) | ((i >> 3) << 2);
  int rp = r >> 1, hf = (r & 1) * 16;
  int ct = b >> 1, bsel = b & 1;
  size_t dwb = (size_t)ng * 2048 + (size_t)((nt * 2 + ct) * 8 + rp) * 64 + kh * 32 + bsel * 16;
  const size_t KSTR = (size_t)NGRP * 2048;

  float y0[16], y1[16], y2[16], y3[16];
#pragma unroll
  for (int v = 0; v < 16; ++v) { y0[v] = 0.f; y1[v] = 0.f; y2[v] = 0.f; y3[v] = 0.f; }

  for (int k = 0; k < 16; ++k) {
    const unsigned int* lp = lpb + dwb + (size_t)k * KSTR;
    const float* lcr = lc + ((size_t)b * 16 + k) * 16;
    float q0, q1, q2, q3;
    {
      int c0 = k, c1 = 16 + k, c2 = 32 + k, c3 = 48 + k;
      q0 = qws[((size_t)b * 64 + c0) * NPOS + n] * st[c0] + st[64 + c0];
      q1 = qws[((size_t)b * 64 + c1) * NPOS + n] * st[c1] + st[64 + c1];
      q2 = qws[((size_t)b * 64 + c2) * NPOS + n] * st[c2] + st[64 + c2];
      q3 = qws[((size_t)b * 64 + c3) * NPOS + n] * st[c3] + st[64 + c3];
    }
#pragma unroll
    for (int v = 0; v < 16; ++v) {
      unsigned int d = lp[v];
      float lam = __uint_as_float(((d >> hf) & 0xFFFFu) << 16) + lcr[v];
      y0[v] += q0 * lam; y1[v] += q1 * lam; y2[v] += q2 * lam; y3[v] += q3 * lam;
    }
  }
#pragma unroll
  for (int v = 0; v < 16; ++v) {
    out[((size_t)b * 64 + 0 * 16 + v) * NPOS + n] = y0[v];
    out[((size_t)b * 64 + 1 * 16 + v) * NPOS + n] = y1[v];
    out[((size_t)b * 64 + 2 * 16 + v) * NPOS + n] = y2[v];
    out[((size_t)b * 64 + 3 * 16 + v) * NPOS + n] = y3[v];
  }
}

extern "C" void kernel_launch(void* const* d_in, const int* in_sizes, int n_in,
                              void* d_out, int out_size, void* d_ws, size_t ws_size,
                              hipStream_t stream) {
  const float* x   = (const float*)d_in[0];
  const float* Wq  = (const float*)d_in[1];
  const float* Wk  = (const float*)d_in[2];
  const float* Wv  = (const float*)d_in[3];
  const float* rpe = (const float*)d_in[4];
  const float* gq  = (const float*)d_in[5];
  const float* bq  = (const float*)d_in[6];
  const float* gv  = (const float*)d_in[7];
  const float* bv  = (const float*)d_in[8];
  float* out = (float*)d_out;
  char* ws = (char*)d_ws;
  float* qws = (float*)(ws + WS_Q);
  float* kws = (float*)(ws + WS_K);
  float* vws = (float*)(ws + WS_V);
  float* st  = (float*)(ws + WS_ST);
  float* la  = (float*)(ws + WS_LA);
  float* lcp = (float*)(ws + WS_LC);
  unsigned short* ebf = (unsigned short*)(ws + WS_E2);
  unsigned int* lpb = (unsigned int*)(ws + WS_LP);
  uint4* vfrag = (uint4*)(ws + WS_VF);

  k_qkv<<<824, 256, 0, stream>>>(x, Wq, Wk, Wv, rpe, qws, kws, vws, ebf, la);
  k_sl<<<336, 256, 0, stream>>>(qws, kws, vws, gq, bq, gv, bv, st, la);
  k_conv2<<<102, 256, 0, stream>>>(vws, st, la, vfrag, lcp);
  k_lam<<<16 * NGRP, 256, 0, stream>>>(ebf, vfrag, lpb);
  k_ep<<<43, 256, 0, stream>>>(lpb, qws, st, lcp, out);
}

// Round 12
// 65.804 us; speedup vs baseline: 2.4850x; 1.0056x over previous
//
#include <hip/hip_runtime.h>
#include <hip/hip_bf16.h>

#define NPOS 2744      // 14^3
#define BB 4
#define BNTOT (BB*NPOS)   // 10976
#define RELVOL 19683   // 27^3
#define EROWS2 19688       // padded elems per k-row (mult of 4)
#define NRT 196            // (zm,ym) m-row-tiles, 16 kslots each (x=0..13 real)
#define NV2 (NRT*2*64)     // 25088 vfrag entries
#define N4T 1024           // lc
#define WCOPY 10368        // LDS window elems per copy
#define WDW 5184           // dwords per copy (WCOPY/2)
#define NGRP 43            // 64-n groups

typedef __bf16 bf16x8 __attribute__((ext_vector_type(8)));
typedef float f32x16 __attribute__((ext_vector_type(16)));

// ---- workspace layout (bytes) ----
#define WS_Q  0u           // f32 [4][64][2744]
#define WS_K  2809856u     // f32 [4][16][2744]  (dead after k_sl; vfrag aliases it)
#define WS_V  3512320u     // f32 [4][16][2744]
#define WS_ST 4214784u     // f32 [160] scale/shift
#define WS_LA 4216192u     // f32 [1088] lc accum
#define WS_LC 4220544u     // f32 [4][16][16]
#define WS_E2 4224640u     // u16 [16][EROWS2] bf16 E table, k-MAJOR (630KB) + 2KB pad
#define WS_LP 4856704u     // u32 [16][43][2][2][8][64] packed bf16 lambda_p (5.64MB)
#define WS_VF WS_K         // uint4 [196][2][64] v B-fragments

__device__ inline unsigned short f2bf(float f) {
  unsigned int u = __float_as_uint(f);
  return (unsigned short)((u + 0x7fffu + ((u >> 16) & 1u)) >> 16);
}
__device__ inline unsigned int fsh(unsigned int hi, unsigned int lo, int shbits) {
  return (unsigned int)(((((unsigned long long)hi) << 32) | lo) >> shbits);
}
__device__ inline unsigned int pk2(float a, float b) {
  return (unsigned int)f2bf(a) | ((unsigned int)f2bf(b) << 16);
}

// ---------------- P1: qkv projections (blocks 0..515) + E-table build + la-zero (516..823) ----------------
__global__ __launch_bounds__(256) void k_qkv(const float* __restrict__ x,
    const float* __restrict__ Wq, const float* __restrict__ Wk, const float* __restrict__ Wv,
    const float* __restrict__ rpe,
    float* __restrict__ qws, float* __restrict__ kws, float* __restrict__ vws,
    unsigned short* __restrict__ ebf, float* __restrict__ la) {
  int bid = blockIdx.x;
  int tid = threadIdx.x;
  if (bid >= 516) {
    int bid2 = bid - 516;                      // 0..307
    if (bid2 == 0 && tid < 272) ((float4*)la)[tid] = make_float4(0.f, 0.f, 0.f, 0.f);
    const int TOT = 16 * EROWS2 + 1024;        // +1024 elems: zero the 2KB pad after table
    for (int e = bid2 * 256 + tid; e < TOT; e += 308 * 256) {
      if (e < 16 * EROWS2) {
        int k = e / EROWS2;
        int i = e - k * EROWS2;
        float val = (i < RELVOL) ? rpe[i * 16 + k] : 0.f;
        ebf[e] = f2bf(val);
      } else {
        ebf[e] = 0;
      }
    }
    return;
  }
  int cg = bid % 12, nb = bid / 12;
  int gid = nb * 256 + tid;
  if (gid >= BNTOT) return;
  int b = gid / NPOS, n = gid - b * NPOS;
  const float* xp = x + (size_t)b * 64 * NPOS + n;
  int ch0 = cg * 8;
  const float* wbase;
  float* obase;
  if (ch0 < 64)      { wbase = Wq + ch0 * 64;        obase = qws + ((size_t)b * 64 + ch0) * NPOS + n; }
  else if (ch0 < 80) { wbase = Wk + (ch0 - 64) * 64; obase = kws + ((size_t)b * 16 + (ch0 - 64)) * NPOS + n; }
  else               { wbase = Wv + (ch0 - 80) * 64; obase = vws + ((size_t)b * 16 + (ch0 - 80)) * NPOS + n; }

  float acc[8];
#pragma unroll
  for (int j = 0; j < 8; ++j) acc[j] = 0.f;
  for (int c = 0; c < 64; c += 4) {
    float x0 = xp[(c + 0) * NPOS], x1 = xp[(c + 1) * NPOS];
    float x2 = xp[(c + 2) * NPOS], x3 = xp[(c + 3) * NPOS];
#pragma unroll
    for (int j = 0; j < 8; ++j) {
      float4 w = *(const float4*)(wbase + j * 64 + c);
      acc[j] += w.x * x0 + w.y * x1 + w.z * x2 + w.w * x3;
    }
  }
#pragma unroll
  for (int j = 0; j < 8; ++j) obase[(size_t)j * NPOS] = acc[j];
}

// ---------------- P2: BN stats+finalize (blocks 0..79) | lambda_c partials (80..335) ----------------
__global__ __launch_bounds__(256) void k_sl(const float* __restrict__ qws,
    const float* __restrict__ kws, const float* __restrict__ vws,
    const float* __restrict__ gq, const float* __restrict__ bq,
    const float* __restrict__ gv, const float* __restrict__ bv,
    float* __restrict__ st, float* __restrict__ lcacc) {
  int bid = blockIdx.x;
  int tid = threadIdx.x;
  int wid = tid >> 6;
  __shared__ float red[17][4];
  if (bid < 80) {
    int ch = bid;
    const float* p = (ch < 64) ? (qws + (size_t)ch * NPOS) : (vws + (size_t)(ch - 64) * NPOS);
    size_t pstride = (ch < 64) ? (size_t)64 * NPOS : (size_t)16 * NPOS;
    float s = 0.f, ss = 0.f;
    for (int b = 0; b < 4; ++b) {
      const float* pp = p + b * pstride;
      for (int n = tid; n < NPOS; n += 256) { float v = pp[n]; s += v; ss += v * v; }
    }
#pragma unroll
    for (int o = 32; o > 0; o >>= 1) { s += __shfl_xor(s, o, 64); ss += __shfl_xor(ss, o, 64); }
    if ((tid & 63) == 0) { red[0][wid] = s; red[1][wid] = ss; }
    __syncthreads();
    if (tid == 0) {
      float S = red[0][0] + red[0][1] + red[0][2] + red[0][3];
      float SS = red[1][0] + red[1][1] + red[1][2] + red[1][3];
      float mean = S / (float)BNTOT;
      float var = SS / (float)BNTOT - mean * mean;
      float inv = rsqrtf(var + 1e-5f);
      float g, be;
      if (ch < 64) { g = gq[ch]; be = bq[ch]; } else { g = gv[ch - 64]; be = bv[ch - 64]; }
      float sc = g * inv, sh = be - mean * sc;
      if (ch < 64) { st[ch] = sc; st[64 + ch] = sh; }
      else { st[128 + (ch - 64)] = sc; st[144 + (ch - 64)] = sh; }
    }
  } else {
    int bid2 = bid - 80;
    int b = bid2 >> 6, kc = (bid2 >> 2) & 15, seg = bid2 & 3;
    const float* kp = kws + ((size_t)b * 16 + kc) * NPOS;
    const float* vp = vws + (size_t)b * 16 * NPOS;
    float s = 0.f, acc[16];
#pragma unroll
    for (int v = 0; v < 16; ++v) acc[v] = 0.f;
    int m0 = seg * 686;
    for (int m = m0 + tid; m < m0 + 686; m += 256) {
      float e = __expf(kp[m]);
      s += e;
#pragma unroll
      for (int v = 0; v < 16; ++v) acc[v] += e * vp[(size_t)v * NPOS + m];
    }
#pragma unroll
    for (int o = 32; o > 0; o >>= 1) {
      s += __shfl_xor(s, o, 64);
#pragma unroll
      for (int v = 0; v < 16; ++v) acc[v] += __shfl_xor(acc[v], o, 64);
    }
    if ((tid & 63) == 0) { red[16][wid] = s; for (int v = 0; v < 16; ++v) red[v][wid] = acc[v]; }
    __syncthreads();
    if (tid < 17) {
      float tot = red[tid][0] + red[tid][1] + red[tid][2] + red[tid][3];
      atomicAdd(lcacc + ((size_t)b * 16 + kc) * 17 + tid, tot);
    }
  }
}

// ---------------- P3: vfrag (x-row tiling) + lc finalize ----------------
__global__ __launch_bounds__(256) void k_conv2(const float* __restrict__ vws,
    const float* __restrict__ st, const float* __restrict__ lcacc,
    uint4* __restrict__ vfrag, float* __restrict__ lc) {
  int idx = blockIdx.x * 256 + threadIdx.x;
  if (idx < NV2) {
    int rt = idx >> 7; int r = idx & 127;
    int ct = r >> 6, l = r & 63;
    int zm = rt / 14, ym = rt - zm * 14;
    int kh = l >> 5;
    int b = ct * 2 + ((l >> 4) & 1), v = l & 15;
    int mrow = zm * 196 + ym * 14;
    float sc = st[128 + v], sh = st[144 + v];
    unsigned int wds[4];
#pragma unroll
    for (int i = 0; i < 4; ++i) {
      int x0 = kh * 8 + 2 * i, x1 = x0 + 1;
      float f0 = 0.f, f1 = 0.f;
      if (x0 < 14) f0 = vws[((size_t)b * 16 + v) * NPOS + mrow + x0] * sc + sh;
      if (x1 < 14) f1 = vws[((size_t)b * 16 + v) * NPOS + mrow + x1] * sc + sh;
      wds[i] = (unsigned int)f2bf(f0) | ((unsigned int)f2bf(f1) << 16);
    }
    vfrag[(rt * 2 + ct) * 64 + l] = make_uint4(wds[0], wds[1], wds[2], wds[3]);
  } else if (idx < NV2 + N4T) {
    int t = idx - NV2;
    int b = t >> 8, kc = (t >> 4) & 15, v = t & 15;
    const float* la = lcacc + ((size_t)b * 16 + kc) * 17;
    float S = la[16];
    lc[((size_t)b * 16 + kc) * 16 + v] = st[128 + v] * (la[v] / S) + st[144 + v];
  }
}

// ---------------- P4: lambda_p — per-k LDS-windowed MFMA, A+B both 1-deep pipelined ----------------
__global__ __launch_bounds__(256, 3) void k_lam(const unsigned short* __restrict__ ebf,
    const uint4* __restrict__ vfrag, unsigned int* __restrict__ lpb) {
  __shared__ unsigned int lds[WCOPY];
  int tid = threadIdx.x;
  int w = tid >> 6, l = tid & 63;
  int bid = blockIdx.x;
  int k = bid / NGRP, ng = bid - k * NGRP;
  int n0 = ng * 64;
  int nmax = min(n0 + 63, NPOS - 1);
  int zx = nmax / 196, tx = nmax - zx * 196, yx = tx / 14, xx = tx - yx * 14;
  int b0 = (9841 - (zx * 729 + yx * 27 + xx)) & ~7;   // 16B-aligned window start

  // stage window + shifted copy (global dwords aligned; overrun covered by table pad)
  const unsigned int* gsrc = (const unsigned int*)(ebf + (size_t)k * EROWS2 + b0);
#pragma unroll
  for (int it = 0; it < 6; ++it) {
    int ck = it * 256 + tid;
    if (ck < WDW / 4) {
      uint4 g = *(const uint4*)(gsrc + 4 * ck);
      unsigned int g4 = gsrc[4 * ck + 4];
      *(uint4*)(&lds[4 * ck]) = g;
      uint4 h;
      h.x = fsh(g.y, g.x, 16); h.y = fsh(g.z, g.y, 16);
      h.z = fsh(g.w, g.z, 16); h.w = fsh(g4, g.w, 16);
      *(uint4*)(&lds[WDW + 4 * ck]) = h;
    }
  }
  int i = l & 31, kh = l >> 5;
  int n_a = min(n0 + i, NPOS - 1);
  int n_b = min(n0 + 32 + i, NPOS - 1);
  int za = n_a / 196, ta = n_a - za * 196, ya = ta / 14, xa = ta - ya * 14;
  int zb = n_b / 196, tb = n_b - zb * 196, yb = tb / 14, xb = tb - yb * 14;
  int soff0 = (9841 - (za * 729 + ya * 27 + xa)) - b0 + kh * 8;
  int soff1 = (9841 - (zb * 729 + yb * 27 + xb)) - b0 + kh * 8;
  __syncthreads();

  f32x16 a00, a01, a10, a11;
#pragma unroll
  for (int q = 0; q < 16; ++q) { a00[q] = 0.f; a01[q] = 0.f; a10[q] = 0.f; a11[q] = 0.f; }

  int rt0 = w * 49;
  const uint4* vf = vfrag + l;
  // prologue: A and B for d=0
  uint4 A0, A1, B0, B1;
  {
    int zm = rt0 / 14, ym = rt0 - zm * 14;
    int crow = zm * 729 + ym * 27;
    int o0 = soff0 + crow, o1 = soff1 + crow;
    int ad0 = (o0 >> 1) + (o0 & 1) * WDW;
    int ad1 = (o1 >> 1) + (o1 & 1) * WDW;
    A0 = make_uint4(lds[ad0], lds[ad0 + 1], lds[ad0 + 2], lds[ad0 + 3]);
    A1 = make_uint4(lds[ad1], lds[ad1 + 1], lds[ad1 + 2], lds[ad1 + 3]);
    B0 = vf[(size_t)(rt0 * 2) * 64];
    B1 = vf[(size_t)(rt0 * 2 + 1) * 64];
  }
  for (int d = 0; d < 49; ++d) {
    // next-iter A (LDS) and B (global) issued before this iter's MFMAs
    int rtn = rt0 + ((d < 48) ? d + 1 : d);
    int zm = rtn / 14, ym = rtn - zm * 14;
    int crow = zm * 729 + ym * 27;
    int o0 = soff0 + crow, o1 = soff1 + crow;
    int ad0 = (o0 >> 1) + (o0 & 1) * WDW;
    int ad1 = (o1 >> 1) + (o1 & 1) * WDW;
    uint4 nA0 = make_uint4(lds[ad0], lds[ad0 + 1], lds[ad0 + 2], lds[ad0 + 3]);
    uint4 nA1 = make_uint4(lds[ad1], lds[ad1 + 1], lds[ad1 + 2], lds[ad1 + 3]);
    uint4 nB0 = vf[(size_t)(rtn * 2) * 64];
    uint4 nB1 = vf[(size_t)(rtn * 2 + 1) * 64];
    __builtin_amdgcn_s_setprio(1);
    a00 = __builtin_amdgcn_mfma_f32_32x32x16_bf16(
        __builtin_bit_cast(bf16x8, A0), __builtin_bit_cast(bf16x8, B0), a00, 0, 0, 0);
    a01 = __builtin_amdgcn_mfma_f32_32x32x16_bf16(
        __builtin_bit_cast(bf16x8, A0), __builtin_bit_cast(bf16x8, B1), a01, 0, 0, 0);
    a10 = __builtin_amdgcn_mfma_f32_32x32x16_bf16(
        __builtin_bit_cast(bf16x8, A1), __builtin_bit_cast(bf16x8, B0), a10, 0, 0, 0);
    a11 = __builtin_amdgcn_mfma_f32_32x32x16_bf16(
        __builtin_bit_cast(bf16x8, A1), __builtin_bit_cast(bf16x8, B1), a11, 0, 0, 0);
    __builtin_amdgcn_s_setprio(0);
    A0 = nA0; A1 = nA1; B0 = nB0; B1 = nB1;
  }

  // ---- tree reduction over m-quarter waves (reuse window LDS) ----
  __syncthreads();
  float* red = (float*)lds;
  if (w >= 2) {
    float* r0 = red + (w - 2) * 4096;
#pragma unroll
    for (int r = 0; r < 16; ++r) {
      r0[r * 64 + l] = a00[r];          r0[1024 + r * 64 + l] = a01[r];
      r0[2048 + r * 64 + l] = a10[r];   r0[3072 + r * 64 + l] = a11[r];
    }
  }
  __syncthreads();
  if (w < 2) {
    const float* r0 = red + w * 4096;
#pragma unroll
    for (int r = 0; r < 16; ++r) {
      a00[r] += r0[r * 64 + l];         a01[r] += r0[1024 + r * 64 + l];
      a10[r] += r0[2048 + r * 64 + l];  a11[r] += r0[3072 + r * 64 + l];
    }
  }
  __syncthreads();
  if (w == 1) {
#pragma unroll
    for (int r = 0; r < 16; ++r) {
      red[r * 64 + l] = a00[r];         red[1024 + r * 64 + l] = a01[r];
      red[2048 + r * 64 + l] = a10[r];  red[3072 + r * 64 + l] = a11[r];
    }
  }
  __syncthreads();
  if (w == 0) {
#pragma unroll
    for (int r = 0; r < 16; ++r) {
      a00[r] += red[r * 64 + l];        a01[r] += red[1024 + r * 64 + l];
      a10[r] += red[2048 + r * 64 + l]; a11[r] += red[3072 + r * 64 + l];
    }
    // store packed bf16 lambda_p: [k][ng][nt][ct][rp][64]
    size_t base = (size_t)(k * NGRP + ng) * 2048;
#pragma unroll
    for (int rp = 0; rp < 8; ++rp) {
      lpb[base + (size_t)(0 * 8 + rp) * 64 + l]  = pk2(a00[2 * rp], a00[2 * rp + 1]);
      lpb[base + (size_t)(1 * 8 + rp) * 64 + l]  = pk2(a01[2 * rp], a01[2 * rp + 1]);
      lpb[base + (size_t)(2 * 8 + rp) * 64 + l]  = pk2(a10[2 * rp], a10[2 * rp + 1]);
      lpb[base + (size_t)(3 * 8 + rp) * 64 + l]  = pk2(a11[2 * rp], a11[2 * rp + 1]);
    }
  }
}

// ---------------- P5: epilogue out = q_bn . (lambda_p + lambda_c) ----------------
// grid = 688 blocks: bid = (h*4 + vq)*43 + nb. Thread: one (b,n), one h, 4 v's.
__global__ __launch_bounds__(256) void k_ep(const unsigned int* __restrict__ lpb,
    const float* __restrict__ qws, const float* __restrict__ st,
    const float* __restrict__ lc, float* __restrict__ out) {
  int bid = blockIdx.x;
  int nb = bid % 43, hv = bid / 43;
  int h = hv >> 2, vq = hv & 3;
  int gid = nb * 256 + threadIdx.x;
  if (gid >= BNTOT) return;
  int b = gid / NPOS, n = gid - b * NPOS;
  int ng = n >> 6, loc = n & 63, nt = loc >> 5, i = loc & 31;
  int kh = (i >> 2) & 1;
  int r = (i & 3) | ((i >> 3) << 2);
  int rp = r >> 1, hf = (r & 1) * 16;
  int ct = b >> 1, bsel = b & 1;
  size_t dwb = (size_t)ng * 2048 + (size_t)((nt * 2 + ct) * 8 + rp) * 64 + kh * 32 + bsel * 16 + vq * 4;
  const size_t KSTR = (size_t)NGRP * 2048;

  float y0 = 0.f, y1 = 0.f, y2 = 0.f, y3 = 0.f;
  for (int k = 0; k < 16; ++k) {
    uint4 d = *(const uint4*)(lpb + dwb + (size_t)k * KSTR);
    const float* lcr = lc + ((size_t)b * 16 + k) * 16 + vq * 4;
    int ch = h * 16 + k;
    float q = qws[((size_t)b * 64 + ch) * NPOS + n] * st[ch] + st[64 + ch];
    y0 += q * (__uint_as_float(((d.x >> hf) & 0xFFFFu) << 16) + lcr[0]);
    y1 += q * (__uint_as_float(((d.y >> hf) & 0xFFFFu) << 16) + lcr[1]);
    y2 += q * (__uint_as_float(((d.z >> hf) & 0xFFFFu) << 16) + lcr[2]);
    y3 += q * (__uint_as_float(((d.w >> hf) & 0xFFFFu) << 16) + lcr[3]);
  }
  size_t ob = ((size_t)b * 64 + h * 16 + vq * 4) * NPOS + n;
  out[ob] = y0;
  out[ob + (size_t)NPOS] = y1;
  out[ob + (size_t)2 * NPOS] = y2;
  out[ob + (size_t)3 * NPOS] = y3;
}

extern "C" void kernel_launch(void* const* d_in, const int* in_sizes, int n_in,
                              void* d_out, int out_size, void* d_ws, size_t ws_size,
                              hipStream_t stream) {
  const float* x   = (const float*)d_in[0];
  const float* Wq  = (const float*)d_in[1];
  const float* Wk  = (const float*)d_in[2];
  const float* Wv  = (const float*)d_in[3];
  const float* rpe = (const float*)d_in[4];
  const float* gq  = (const float*)d_in[5];
  const float* bq  = (const float*)d_in[6];
  const float* gv  = (const float*)d_in[7];
  const float* bv  = (const float*)d_in[8];
  float* out = (float*)d_out;
  char* ws = (char*)d_ws;
  float* qws = (float*)(ws + WS_Q);
  float* kws = (float*)(ws + WS_K);
  float* vws = (float*)(ws + WS_V);
  float* st  = (float*)(ws + WS_ST);
  float* la  = (float*)(ws + WS_LA);
  float* lcp = (float*)(ws + WS_LC);
  unsigned short* ebf = (unsigned short*)(ws + WS_E2);
  unsigned int* lpb = (unsigned int*)(ws + WS_LP);
  uint4* vfrag = (uint4*)(ws + WS_VF);

  k_qkv<<<824, 256, 0, stream>>>(x, Wq, Wk, Wv, rpe, qws, kws, vws, ebf, la);
  k_sl<<<336, 256, 0, stream>>>(qws, kws, vws, gq, bq, gv, bv, st, la);
  k_conv2<<<102, 256, 0, stream>>>(vws, st, la, vfrag, lcp);
  k_lam<<<16 * NGRP, 256, 0, stream>>>(ebf, vfrag, lpb);
  k_ep<<<688, 256, 0, stream>>>(lpb, qws, st, lcp, out);
}